// Round 12
// baseline (211.901 us; speedup 1.0000x reference)
//
#include <hip/hip_runtime.h>

#define BB 4
#define CC 256
#define NN 4096
#define CNT (CC*NN)

typedef float f32x4 __attribute__((ext_vector_type(4)));
typedef short bf16x8 __attribute__((ext_vector_type(8)));

__device__ inline ushort f2bf(float f) {
    union { float f; uint u; } v; v.f = f;
    uint r = v.u + 0x7fff + ((v.u >> 16) & 1);
    return (ushort)(r >> 16);
}

__device__ inline uint cvt_pk_bf16(float a, float b) {
    uint r;
    asm("v_cvt_pk_bf16_f32 %0, %1, %2" : "=v"(r) : "v"(a), "v"(b));
    return r;
}

#define MFMA16(d, a, b) d = __builtin_amdgcn_mfma_f32_16x16x32_bf16(a, b, d, 0, 0, 0)

// ---------------- weight prep: fp32 -> bf16 (Q rows pre-scaled by 2^-4*log2e) ----------------
__global__ __launch_bounds__(256) void prep_w(const float* __restrict__ qkv_w,
                                              const float* __restrict__ proj_w,
                                              ushort* __restrict__ wq,
                                              ushort* __restrict__ wp) {
    int idx = blockIdx.x * 256 + threadIdx.x;       // one f32x4 each
    if (idx < 49152) {                               // qkv: 768*256 = 49152 x4
        int row = (idx * 4) >> 8;
        float sc = (row < 256) ? 0.0625f * 1.4426950408889634f : 1.0f;
        f32x4 v = *(const f32x4*)(qkv_w + (size_t)idx * 4);
        ushort4 o;
        o.x = f2bf(v.x * sc); o.y = f2bf(v.y * sc);
        o.z = f2bf(v.z * sc); o.w = f2bf(v.w * sc);
        *(ushort4*)(wq + (size_t)idx * 4) = o;
    } else {
        int j = idx - 49152;                         // proj: 256*256 = 16384 x4
        f32x4 v = *(const f32x4*)(proj_w + (size_t)j * 4);
        ushort4 o;
        o.x = f2bf(v.x); o.y = f2bf(v.y); o.z = f2bf(v.z); o.w = f2bf(v.w);
        *(ushort4*)(wp + (size_t)j * 4) = o;
    }
}

// ---------------- stats: deterministic two-stage sum/sumsq per batch ----------------
__global__ __launch_bounds__(256) void stats_part(const float* __restrict__ x,
                                                  float* __restrict__ part) {
    int b = blockIdx.y;
    const float* xb = x + b * CNT;
    float s = 0.f, q = 0.f;
    int base = (blockIdx.x * 256 + threadIdx.x) * 4;
    for (int i = base; i < CNT; i += 64 * 256 * 4) {
        f32x4 v = *(const f32x4*)(xb + i);
        s += (v.x + v.y) + (v.z + v.w);
        q += (v.x * v.x + v.y * v.y) + (v.z * v.z + v.w * v.w);
    }
    for (int off = 32; off; off >>= 1) {
        s += __shfl_down(s, off, 64);
        q += __shfl_down(q, off, 64);
    }
    __shared__ float red[8];
    int lane = threadIdx.x & 63, wv = threadIdx.x >> 6;
    if (!lane) { red[wv * 2] = s; red[wv * 2 + 1] = q; }
    __syncthreads();
    if (threadIdx.x == 0) {
        part[(b * 64 + blockIdx.x) * 2 + 0] = red[0] + red[2] + red[4] + red[6];
        part[(b * 64 + blockIdx.x) * 2 + 1] = red[1] + red[3] + red[5] + red[7];
    }
}

__global__ __launch_bounds__(256) void stats_final(const float* __restrict__ part,
                                                   float* __restrict__ stats) {
    int t = threadIdx.x;
    int b = t >> 6, lane = t & 63;
    float s = part[(b * 64 + lane) * 2 + 0];
    float q = part[(b * 64 + lane) * 2 + 1];
    for (int off = 32; off; off >>= 1) {
        s += __shfl_down(s, off, 64);
        q += __shfl_down(q, off, 64);
    }
    if (lane == 0) { stats[b * 2] = s; stats[b * 2 + 1] = q; }
}

// ---------------- norm + transpose: x[b][c][n] fp32 -> xn_t[b][n][c] bf16 ----------------
__global__ __launch_bounds__(256) void norm_t_kernel(
    const float* __restrict__ x, const float* __restrict__ gamma,
    const float* __restrict__ beta, const float* __restrict__ stats,
    ushort* __restrict__ xn_t)
{
    int b = blockIdx.z;
    float mean = stats[b * 2] * (1.0f / (float)CNT);
    float var = stats[b * 2 + 1] * (1.0f / (float)CNT) - mean * mean;
    float rinv = rsqrtf(var + 1e-5f);
    int n0 = blockIdx.x * 32, c0 = blockIdx.y * 32;
    __shared__ float tl[32][33];
    int tr = threadIdx.x >> 3;
    int tc4 = (threadIdx.x & 7) * 4;
    int c = c0 + tr;
    float gsc = gamma[c] * rinv;
    float bsc = beta[c] - mean * gsc;
    f32x4 v = *(const f32x4*)(x + ((b * CC + c) * NN + n0 + tc4));
    tl[tr][tc4 + 0] = v.x * gsc + bsc;
    tl[tr][tc4 + 1] = v.y * gsc + bsc;
    tl[tr][tc4 + 2] = v.z * gsc + bsc;
    tl[tr][tc4 + 3] = v.w * gsc + bsc;
    __syncthreads();
    int nr = threadIdx.x >> 3;
    int cg4 = (threadIdx.x & 7) * 4;
    ushort4 o;
    o.x = f2bf(tl[cg4 + 0][nr]);
    o.y = f2bf(tl[cg4 + 1][nr]);
    o.z = f2bf(tl[cg4 + 2][nr]);
    o.w = f2bf(tl[cg4 + 3][nr]);
    *(ushort4*)(xn_t + ((size_t)(b * NN + n0 + nr) * CC + c0 + cg4)) = o;
}

// ---------------- QKV GEMM: bf16 weights, stages B tile once, 6 d-subtiles ----------------
__global__ __launch_bounds__(256) void qkv_kernel(
    const ushort* __restrict__ xn_t, const ushort* __restrict__ wq,
    const float* __restrict__ qkv_b, ushort* __restrict__ q_t,
    ushort* __restrict__ k_t, ushort* __restrict__ v_g)
{
    int b = blockIdx.z;
    int i0 = blockIdx.y * 64;
    int t = threadIdx.x, w = t >> 6, l = t & 63, l15 = l & 15, g = l >> 4;
    __shared__ ushort b_lds[64 * 256];

    #pragma unroll
    for (int it = 0; it < 8; it++) {
        int cid = it * 256 + t;
        int rr = cid >> 5, cc = cid & 31;
        bf16x8 vv = *(const bf16x8*)(xn_t + ((size_t)(b * NN + i0 + rr) * CC + cc * 8));
        *(bf16x8*)(b_lds + rr * 256 + (cc ^ (rr & 7)) * 8) = vv;
    }
    __syncthreads();

    for (int ds = 0; ds < 6; ds++) {
        int d0 = blockIdx.x * 384 + ds * 64;
        int drow = d0 + w * 16 + l15;
        bf16x8 af[8];
        #pragma unroll
        for (int kk = 0; kk < 8; kk++)
            af[kk] = *(const bf16x8*)(wq + (size_t)drow * CC + kk * 32 + g * 8);

        f32x4 acc[4];
        #pragma unroll
        for (int it = 0; it < 4; it++) { f32x4 z = {0.f, 0.f, 0.f, 0.f}; acc[it] = z; }
        #pragma unroll
        for (int kk = 0; kk < 8; kk++) {
            int cc = kk * 4 + g;
            #pragma unroll
            for (int it = 0; it < 4; it++) {
                int il = it * 16 + l15;
                bf16x8 bf = *(const bf16x8*)(b_lds + il * 256 + (cc ^ (il & 7)) * 8);
                MFMA16(acc[it], af[kk], bf);
            }
        }
        int dbase = d0 + w * 16 + g * 4;
        f32x4 bias = *(const f32x4*)(qkv_b + dbase);
        float bs = (d0 < 256) ? 0.0625f * 1.4426950408889634f : 1.0f;  // acc already scaled
        #pragma unroll
        for (int it = 0; it < 4; it++) {
            int i = i0 + it * 16 + l15;
            if (d0 < 512) {
                ushort4 o;
                o.x = f2bf(acc[it][0] + bias[0] * bs);
                o.y = f2bf(acc[it][1] + bias[1] * bs);
                o.z = f2bf(acc[it][2] + bias[2] * bs);
                o.w = f2bf(acc[it][3] + bias[3] * bs);
                ushort* dst = (d0 < 256) ? q_t : k_t;
                int dl = dbase - ((d0 < 256) ? 0 : 256);
                *(ushort4*)(dst + ((size_t)(b * NN + i) * CC + dl)) = o;
            } else {
                #pragma unroll
                for (int e = 0; e < 4; e++)
                    v_g[(size_t)(b * CC + (dbase - 512 + e)) * NN + i] = f2bf(acc[it][e] + bias[e]);
            }
        }
    }
}

// ---------------- flash attention: swapped QK^T, p_lds PV (R10), T14 split staging ----------------
// Next-tile global loads issue after softmax (hide under PV); LDS writes after PV.
__global__ __launch_bounds__(512, 2) void flash_kernel(
    const ushort* __restrict__ q_t, const ushort* __restrict__ k_t,
    const ushort* __restrict__ v_g, float* __restrict__ O_part,
    float* __restrict__ l_part, int segn)
{
    int b = blockIdx.z, seg = blockIdx.y;
    int i0 = blockIdx.x * 256;
    int jbase = seg * segn;
    int t = threadIdx.x, w = t >> 6, l = t & 63, l15 = l & 15, g = l >> 4;

    __shared__ ushort k_lds[2][32 * 256];  // [j][16B chunk ^ (j&7)]
    __shared__ ushort v_lds[2][256 * 32];  // [c][16B chunk ^ s4(c)]
    __shared__ ushort p_lds[256 * 32];     // [r][16B chunk ^ (r&3)]

    bf16x8 qf0[8], qf1[8];
    const ushort* qr0 = q_t + (size_t)(b * NN + i0 + w * 32 + l15) * CC + g * 8;
    #pragma unroll
    for (int kk = 0; kk < 8; kk++) qf0[kk] = *(const bf16x8*)(qr0 + kk * 32);
    const ushort* qr1 = qr0 + (size_t)16 * CC;
    #pragma unroll
    for (int kk = 0; kk < 8; kk++) qf1[kk] = *(const bf16x8*)(qr1 + kk * 32);

    f32x4 O0[16], O1[16];
    #pragma unroll
    for (int tc = 0; tc < 16; tc++) {
        f32x4 z = {0.f, 0.f, 0.f, 0.f};
        O0[tc] = z; O1[tc] = z;
    }
    float l0 = 0.f, l1 = 0.f;

    const ushort* kb = k_t + (size_t)b * NN * CC;
    const ushort* vb = v_g + (size_t)b * CC * NN;

    // prologue: full stage of tile 0
    {
        bf16x8 kr[2], vr[2];
        #pragma unroll
        for (int is = 0; is < 2; is++) {
            int s = is * 512 + t;
            kr[is] = *(const bf16x8*)(kb + (size_t)(jbase + (s >> 5)) * CC + (s & 31) * 8);
            vr[is] = *(const bf16x8*)(vb + (size_t)(s >> 2) * NN + jbase + (s & 3) * 8);
        }
        #pragma unroll
        for (int is = 0; is < 2; is++) {
            int s = is * 512 + t;
            int jr = s >> 5, cc = s & 31;
            *(bf16x8*)((ushort*)k_lds[0] + jr * 256 + ((cc ^ (jr & 7)) * 8)) = kr[is];
            int cr = s >> 2, cv = s & 3;
            *(bf16x8*)((ushort*)v_lds[0] + cr * 32 + ((cv ^ ((cr ^ (cr >> 2)) & 3)) * 8)) = vr[is];
        }
    }

    int niter = segn >> 5;
    int r0 = w * 32 + l15;
    int half = (g & 1) * 4;

    for (int it = 0; it < niter; it++) {
        int d = it & 1;
        __syncthreads();
        const ushort* kl = k_lds[d];
        const ushort* vl = v_lds[d];
        bool more = (it + 1 < niter);

        // S^T = K Q^T per 16-j group: lane holds S[j=jg*16+g*4+e][i=l15]
        #pragma unroll
        for (int jg = 0; jg < 2; jg++) {
            f32x4 s0 = {0.f, 0.f, 0.f, 0.f}, s1 = {0.f, 0.f, 0.f, 0.f};
            int j = jg * 16 + l15;
            const ushort* krow = kl + j * 256;
            int xj = j & 7;
            __builtin_amdgcn_s_setprio(1);
            #pragma unroll
            for (int kk = 0; kk < 8; kk++) {
                bf16x8 bk = *(const bf16x8*)(krow + (((kk * 4 + g) ^ xj) * 8));
                MFMA16(s0, bk, qf0[kk]);      // swapped: A=K, B=Q
                MFMA16(s1, bk, qf1[kk]);
            }
            __builtin_amdgcn_s_setprio(0);

            float p00 = exp2f(s0[0]), p01 = exp2f(s0[1]);
            float p02 = exp2f(s0[2]), p03 = exp2f(s0[3]);
            float p10 = exp2f(s1[0]), p11 = exp2f(s1[1]);
            float p12 = exp2f(s1[2]), p13 = exp2f(s1[3]);
            l0 += (p00 + p01) + (p02 + p03);
            l1 += (p10 + p11) + (p12 + p13);
            uint lo0 = cvt_pk_bf16(p00, p01), hi0 = cvt_pk_bf16(p02, p03);
            uint lo1 = cvt_pk_bf16(p10, p11), hi1 = cvt_pk_bf16(p12, p13);
            int c16 = jg * 2 + (g >> 1);
            uint2 u0; u0.x = lo0; u0.y = hi0;
            uint2 u1; u1.x = lo1; u1.y = hi1;
            *(uint2*)(p_lds + r0 * 32 + ((c16 ^ (r0 & 3)) * 8) + half) = u0;
            int r1 = r0 + 16;
            *(uint2*)(p_lds + r1 * 32 + ((c16 ^ (r1 & 3)) * 8) + half) = u1;
        }

        // T14 split: issue next-tile global loads NOW (hide under PV)
        bf16x8 kr[2], vr[2];
        if (more) {
            int jt = jbase + (it + 1) * 32;
            #pragma unroll
            for (int is = 0; is < 2; is++) {
                int s = is * 512 + t;
                kr[is] = *(const bf16x8*)(kb + (size_t)(jt + (s >> 5)) * CC + (s & 31) * 8);
                vr[is] = *(const bf16x8*)(vb + (size_t)(s >> 2) * NN + jt + (s & 3) * 8);
            }
        }

        // P A-fragments (wave-private rows; lgkmcnt orders write->read)
        bf16x8 pa0 = *(const bf16x8*)(p_lds + r0 * 32 + ((g ^ (r0 & 3)) * 8));
        int r1 = r0 + 16;
        bf16x8 pa1 = *(const bf16x8*)(p_lds + r1 * 32 + ((g ^ (r1 & 3)) * 8));

        // O += P V^T (V fragment shared by both row-blocks)
        __builtin_amdgcn_s_setprio(1);
        #pragma unroll
        for (int tc = 0; tc < 16; tc++) {
            int c = tc * 16 + l15;
            bf16x8 vf = *(const bf16x8*)(vl + c * 32 + ((g ^ ((c ^ (c >> 2)) & 3)) * 8));
            MFMA16(O0[tc], pa0, vf);
            MFMA16(O1[tc], pa1, vf);
        }
        __builtin_amdgcn_s_setprio(0);

        // write staged regs into the other buffer
        if (more) {
            #pragma unroll
            for (int is = 0; is < 2; is++) {
                int s = is * 512 + t;
                int jr = s >> 5, cc = s & 31;
                *(bf16x8*)((ushort*)k_lds[d ^ 1] + jr * 256 + ((cc ^ (jr & 7)) * 8)) = kr[is];
                int cr = s >> 2, cv = s & 3;
                *(bf16x8*)((ushort*)v_lds[d ^ 1] + cr * 32 + ((cv ^ ((cr ^ (cr >> 2)) & 3)) * 8)) = vr[is];
            }
        }
    }

    // l lives per (l15, g): reduce across the 4 g-groups
    l0 += __shfl_xor(l0, 16, 64); l1 += __shfl_xor(l1, 16, 64);
    l0 += __shfl_xor(l0, 32, 64); l1 += __shfl_xor(l1, 32, 64);

    size_t obase = (size_t)(seg * BB + b) * NN + i0;
    if (g == 0) {
        l_part[obase + w * 32 + l15] = l0;
        l_part[obase + w * 32 + 16 + l15] = l1;
    }
    #pragma unroll
    for (int e = 0; e < 4; e++) {
        int ro = w * 32 + g * 4 + e;
        float* orow0 = O_part + (obase + ro) * CC + l15;
        float* orow1 = O_part + (obase + ro + 16) * CC + l15;
        #pragma unroll
        for (int tc = 0; tc < 16; tc++) {
            orow0[tc * 16] = O0[tc][e];
            orow1[tc * 16] = O1[tc][e];
        }
    }
}

// ---------------- merge partial segments -> out_t bf16 (fully coalesced) ----------------
__global__ __launch_bounds__(256) void merge_kernel(
    const float* __restrict__ O_part, const float* __restrict__ l_part,
    ushort* __restrict__ out_t, int S)
{
    int idx = blockIdx.x * 256 + threadIdx.x;
    int row = idx >> 6;
    float lsum = 0.f;
    for (int s = 0; s < S; s++) lsum += l_part[(size_t)s * BB * NN + row];
    float inv = 1.0f / fmaxf(lsum, 1e-20f);

    f32x4 acc = {0.f, 0.f, 0.f, 0.f};
    for (int s = 0; s < S; s++) {
        f32x4 v = *(const f32x4*)(O_part + ((size_t)s * BB * NN * CC) + (size_t)idx * 4);
        acc.x += v.x; acc.y += v.y; acc.z += v.z; acc.w += v.w;
    }
    ushort4 o;
    o.x = f2bf(acc.x * inv);
    o.y = f2bf(acc.y * inv);
    o.z = f2bf(acc.z * inv);
    o.w = f2bf(acc.w * inv);
    *(ushort4*)(out_t + (size_t)idx * 4) = o;
}

// ---------------- proj GEMM + bias + residual (bf16 weights) ----------------
__global__ __launch_bounds__(256) void proj_kernel(
    const ushort* __restrict__ out_t, const ushort* __restrict__ wp,
    const float* __restrict__ proj_b, const float* __restrict__ x,
    float* __restrict__ out)
{
    int b = blockIdx.z;
    int d0 = blockIdx.x * 64;
    int i0 = blockIdx.y * 256;
    int t = threadIdx.x, w = t >> 6, l = t & 63, l15 = l & 15, g = l >> 4;
    __shared__ ushort a_lds[64 * 256];

    #pragma unroll
    for (int it = 0; it < 8; it++) {
        int cid = it * 256 + t;
        int dd = cid >> 5, cc = cid & 31;
        bf16x8 a = *(const bf16x8*)(wp + (size_t)(d0 + dd) * CC + cc * 8);
        *(bf16x8*)(a_lds + dd * 256 + (cc ^ (dd & 7)) * 8) = a;
    }
    __syncthreads();

    f32x4 acc[16];
    #pragma unroll
    for (int it = 0; it < 16; it++) { f32x4 z = {0.f, 0.f, 0.f, 0.f}; acc[it] = z; }
    int dl = w * 16 + l15;
    #pragma unroll
    for (int kk = 0; kk < 8; kk++) {
        int cc = kk * 4 + g;
        bf16x8 af = *(const bf16x8*)(a_lds + dl * 256 + (cc ^ (dl & 7)) * 8);
        #pragma unroll
        for (int it = 0; it < 16; it++) {
            bf16x8 bfr = *(const bf16x8*)(out_t + (size_t)(b * NN + i0 + it * 16 + l15) * CC + kk * 32 + g * 8);
            MFMA16(acc[it], af, bfr);
        }
    }
    int dbase = d0 + w * 16 + g * 4;
    f32x4 pb = *(const f32x4*)(proj_b + dbase);
    #pragma unroll
    for (int it = 0; it < 16; it++) {
        int i = i0 + it * 16 + l15;
        #pragma unroll
        for (int e = 0; e < 4; e++) {
            int off = (b * CC + dbase + e) * NN + i;
            out[off] = acc[it][e] + pb[e] + x[off];
        }
    }
}

extern "C" void kernel_launch(void* const* d_in, const int* in_sizes, int n_in,
                              void* d_out, int out_size, void* d_ws, size_t ws_size,
                              hipStream_t stream) {
    const float* x      = (const float*)d_in[0];
    const float* gamma  = (const float*)d_in[1];
    const float* beta   = (const float*)d_in[2];
    const float* qkv_w  = (const float*)d_in[3];
    const float* qkv_b  = (const float*)d_in[4];
    const float* proj_w = (const float*)d_in[5];
    const float* proj_b = (const float*)d_in[6];
    float* out = (float*)d_out;

    char* ws = (char*)d_ws;
    float* part   = (float*)ws;                       // 2048 B
    float* stats  = (float*)(ws + 2048);              // to 4096
    ushort* wq    = (ushort*)(ws + 4096);             // 384 KiB
    ushort* wp    = (ushort*)(ws + 4096 + 393216);    // 128 KiB -> ends 528384
    ushort* xn_t  = (ushort*)(ws + 528384);
    ushort* q_t   = (ushort*)(ws + 528384 + 1ull * 8388608);
    ushort* k_t   = (ushort*)(ws + 528384 + 2ull * 8388608);
    ushort* v_g   = (ushort*)(ws + 528384 + 3ull * 8388608);
    ushort* out_t = xn_t;

    size_t mlbase = 528384 + 4ull * 8388608;
    float* l_part = (float*)(ws + mlbase);
    size_t obase  = mlbase + 1048576;
    float* O_part = (float*)(ws + obase);

    int S = 1;
    if (ws_size >= obase + 4ull * 16777216) S = 4;
    else if (ws_size >= obase + 2ull * 16777216) S = 2;

    prep_w<<<256, 256, 0, stream>>>(qkv_w, proj_w, wq, wp);
    stats_part<<<dim3(64, 4), 256, 0, stream>>>(x, part);
    stats_final<<<1, 256, 0, stream>>>(part, stats);
    norm_t_kernel<<<dim3(128, 8, 4), 256, 0, stream>>>(x, gamma, beta, stats, xn_t);
    qkv_kernel<<<dim3(2, 64, 4), 256, 0, stream>>>(xn_t, wq, qkv_b, q_t, k_t, v_g);
    flash_kernel<<<dim3(16, S, 4), 512, 0, stream>>>(q_t, k_t, v_g, O_part, l_part, NN / S);
    merge_kernel<<<4096, 256, 0, stream>>>(O_part, l_part, out_t, S);
    proj_kernel<<<dim3(4, 16, 4), 256, 0, stream>>>(out_t, wp, proj_b, x, out);
}

// Round 13
// 192.633 us; speedup vs baseline: 1.1000x; 1.1000x over previous
//
#include <hip/hip_runtime.h>

#define BB 4
#define CC 256
#define NN 4096
#define CNT (CC*NN)

typedef float f32x4 __attribute__((ext_vector_type(4)));
typedef short bf16x8 __attribute__((ext_vector_type(8)));

__device__ inline ushort f2bf(float f) {
    union { float f; uint u; } v; v.f = f;
    uint r = v.u + 0x7fff + ((v.u >> 16) & 1);
    return (ushort)(r >> 16);
}

__device__ inline uint cvt_pk_bf16(float a, float b) {
    uint r;
    asm("v_cvt_pk_bf16_f32 %0, %1, %2" : "=v"(r) : "v"(a), "v"(b));
    return r;
}

#define MFMA16(d, a, b) d = __builtin_amdgcn_mfma_f32_16x16x32_bf16(a, b, d, 0, 0, 0)

// ---------------- weight prep: fp32 -> bf16 (Q rows pre-scaled by 2^-4*log2e) ----------------
__global__ __launch_bounds__(256) void prep_w(const float* __restrict__ qkv_w,
                                              const float* __restrict__ proj_w,
                                              ushort* __restrict__ wq,
                                              ushort* __restrict__ wp) {
    int idx = blockIdx.x * 256 + threadIdx.x;       // one f32x4 each
    if (idx < 49152) {                               // qkv: 768*256 = 49152 x4
        int row = (idx * 4) >> 8;
        float sc = (row < 256) ? 0.0625f * 1.4426950408889634f : 1.0f;
        f32x4 v = *(const f32x4*)(qkv_w + (size_t)idx * 4);
        ushort4 o;
        o.x = f2bf(v.x * sc); o.y = f2bf(v.y * sc);
        o.z = f2bf(v.z * sc); o.w = f2bf(v.w * sc);
        *(ushort4*)(wq + (size_t)idx * 4) = o;
    } else {
        int j = idx - 49152;                         // proj: 256*256 = 16384 x4
        f32x4 v = *(const f32x4*)(proj_w + (size_t)j * 4);
        ushort4 o;
        o.x = f2bf(v.x); o.y = f2bf(v.y); o.z = f2bf(v.z); o.w = f2bf(v.w);
        *(ushort4*)(wp + (size_t)j * 4) = o;
    }
}

// ---------------- stats: deterministic two-stage sum/sumsq per batch ----------------
__global__ __launch_bounds__(256) void stats_part(const float* __restrict__ x,
                                                  float* __restrict__ part) {
    int b = blockIdx.y;
    const float* xb = x + b * CNT;
    float s = 0.f, q = 0.f;
    int base = (blockIdx.x * 256 + threadIdx.x) * 4;
    for (int i = base; i < CNT; i += 64 * 256 * 4) {
        f32x4 v = *(const f32x4*)(xb + i);
        s += (v.x + v.y) + (v.z + v.w);
        q += (v.x * v.x + v.y * v.y) + (v.z * v.z + v.w * v.w);
    }
    for (int off = 32; off; off >>= 1) {
        s += __shfl_down(s, off, 64);
        q += __shfl_down(q, off, 64);
    }
    __shared__ float red[8];
    int lane = threadIdx.x & 63, wv = threadIdx.x >> 6;
    if (!lane) { red[wv * 2] = s; red[wv * 2 + 1] = q; }
    __syncthreads();
    if (threadIdx.x == 0) {
        part[(b * 64 + blockIdx.x) * 2 + 0] = red[0] + red[2] + red[4] + red[6];
        part[(b * 64 + blockIdx.x) * 2 + 1] = red[1] + red[3] + red[5] + red[7];
    }
}

__global__ __launch_bounds__(256) void stats_final(const float* __restrict__ part,
                                                   float* __restrict__ stats) {
    int t = threadIdx.x;
    int b = t >> 6, lane = t & 63;
    float s = part[(b * 64 + lane) * 2 + 0];
    float q = part[(b * 64 + lane) * 2 + 1];
    for (int off = 32; off; off >>= 1) {
        s += __shfl_down(s, off, 64);
        q += __shfl_down(q, off, 64);
    }
    if (lane == 0) { stats[b * 2] = s; stats[b * 2 + 1] = q; }
}

// ---------------- norm + transpose: x[b][c][n] fp32 -> xn_t[b][n][c] bf16 ----------------
__global__ __launch_bounds__(256) void norm_t_kernel(
    const float* __restrict__ x, const float* __restrict__ gamma,
    const float* __restrict__ beta, const float* __restrict__ stats,
    ushort* __restrict__ xn_t)
{
    int b = blockIdx.z;
    float mean = stats[b * 2] * (1.0f / (float)CNT);
    float var = stats[b * 2 + 1] * (1.0f / (float)CNT) - mean * mean;
    float rinv = rsqrtf(var + 1e-5f);
    int n0 = blockIdx.x * 32, c0 = blockIdx.y * 32;
    __shared__ float tl[32][33];
    int tr = threadIdx.x >> 3;
    int tc4 = (threadIdx.x & 7) * 4;
    int c = c0 + tr;
    float gsc = gamma[c] * rinv;
    float bsc = beta[c] - mean * gsc;
    f32x4 v = *(const f32x4*)(x + ((b * CC + c) * NN + n0 + tc4));
    tl[tr][tc4 + 0] = v.x * gsc + bsc;
    tl[tr][tc4 + 1] = v.y * gsc + bsc;
    tl[tr][tc4 + 2] = v.z * gsc + bsc;
    tl[tr][tc4 + 3] = v.w * gsc + bsc;
    __syncthreads();
    int nr = threadIdx.x >> 3;
    int cg4 = (threadIdx.x & 7) * 4;
    ushort4 o;
    o.x = f2bf(tl[cg4 + 0][nr]);
    o.y = f2bf(tl[cg4 + 1][nr]);
    o.z = f2bf(tl[cg4 + 2][nr]);
    o.w = f2bf(tl[cg4 + 3][nr]);
    *(ushort4*)(xn_t + ((size_t)(b * NN + n0 + nr) * CC + c0 + cg4)) = o;
}

// ---------------- QKV GEMM: bf16 weights, stages B tile once, 6 d-subtiles ----------------
__global__ __launch_bounds__(256) void qkv_kernel(
    const ushort* __restrict__ xn_t, const ushort* __restrict__ wq,
    const float* __restrict__ qkv_b, ushort* __restrict__ q_t,
    ushort* __restrict__ k_t, ushort* __restrict__ v_g)
{
    int b = blockIdx.z;
    int i0 = blockIdx.y * 64;
    int t = threadIdx.x, w = t >> 6, l = t & 63, l15 = l & 15, g = l >> 4;
    __shared__ ushort b_lds[64 * 256];

    #pragma unroll
    for (int it = 0; it < 8; it++) {
        int cid = it * 256 + t;
        int rr = cid >> 5, cc = cid & 31;
        bf16x8 vv = *(const bf16x8*)(xn_t + ((size_t)(b * NN + i0 + rr) * CC + cc * 8));
        *(bf16x8*)(b_lds + rr * 256 + (cc ^ (rr & 7)) * 8) = vv;
    }
    __syncthreads();

    for (int ds = 0; ds < 6; ds++) {
        int d0 = blockIdx.x * 384 + ds * 64;
        int drow = d0 + w * 16 + l15;
        bf16x8 af[8];
        #pragma unroll
        for (int kk = 0; kk < 8; kk++)
            af[kk] = *(const bf16x8*)(wq + (size_t)drow * CC + kk * 32 + g * 8);

        f32x4 acc[4];
        #pragma unroll
        for (int it = 0; it < 4; it++) { f32x4 z = {0.f, 0.f, 0.f, 0.f}; acc[it] = z; }
        #pragma unroll
        for (int kk = 0; kk < 8; kk++) {
            int cc = kk * 4 + g;
            #pragma unroll
            for (int it = 0; it < 4; it++) {
                int il = it * 16 + l15;
                bf16x8 bf = *(const bf16x8*)(b_lds + il * 256 + (cc ^ (il & 7)) * 8);
                MFMA16(acc[it], af[kk], bf);
            }
        }
        int dbase = d0 + w * 16 + g * 4;
        f32x4 bias = *(const f32x4*)(qkv_b + dbase);
        float bs = (d0 < 256) ? 0.0625f * 1.4426950408889634f : 1.0f;
        #pragma unroll
        for (int it = 0; it < 4; it++) {
            int i = i0 + it * 16 + l15;
            if (d0 < 512) {
                ushort4 o;
                o.x = f2bf(acc[it][0] + bias[0] * bs);
                o.y = f2bf(acc[it][1] + bias[1] * bs);
                o.z = f2bf(acc[it][2] + bias[2] * bs);
                o.w = f2bf(acc[it][3] + bias[3] * bs);
                ushort* dst = (d0 < 256) ? q_t : k_t;
                int dl = dbase - ((d0 < 256) ? 0 : 256);
                *(ushort4*)(dst + ((size_t)(b * NN + i) * CC + dl)) = o;
            } else {
                #pragma unroll
                for (int e = 0; e < 4; e++)
                    v_g[(size_t)(b * CC + (dbase - 512 + e)) * NN + i] = f2bf(acc[it][e] + bias[e]);
            }
        }
    }
}

// ---------------- flash attention: swapped QK^T (4-chain interleaved), p_lds PV ----------------
// R10 staging placement (proven); jg loops fused so QK^T has 4 independent
// accumulation chains sharing bk loads (j and j+16 rows share xj).
__global__ __launch_bounds__(512, 2) void flash_kernel(
    const ushort* __restrict__ q_t, const ushort* __restrict__ k_t,
    const ushort* __restrict__ v_g, float* __restrict__ O_part,
    float* __restrict__ l_part, int segn)
{
    int b = blockIdx.z, seg = blockIdx.y;
    int i0 = blockIdx.x * 256;
    int jbase = seg * segn;
    int t = threadIdx.x, w = t >> 6, l = t & 63, l15 = l & 15, g = l >> 4;

    __shared__ ushort k_lds[2][32 * 256];  // [j][16B chunk ^ (j&7)]
    __shared__ ushort v_lds[2][256 * 32];  // [c][16B chunk ^ s4(c)]
    __shared__ ushort p_lds[256 * 32];     // [r][16B chunk ^ (r&3)]

    bf16x8 qf0[8], qf1[8];
    const ushort* qr0 = q_t + (size_t)(b * NN + i0 + w * 32 + l15) * CC + g * 8;
    #pragma unroll
    for (int kk = 0; kk < 8; kk++) qf0[kk] = *(const bf16x8*)(qr0 + kk * 32);
    const ushort* qr1 = qr0 + (size_t)16 * CC;
    #pragma unroll
    for (int kk = 0; kk < 8; kk++) qf1[kk] = *(const bf16x8*)(qr1 + kk * 32);

    f32x4 O0[16], O1[16];
    #pragma unroll
    for (int tc = 0; tc < 16; tc++) {
        f32x4 z = {0.f, 0.f, 0.f, 0.f};
        O0[tc] = z; O1[tc] = z;
    }
    float l0 = 0.f, l1 = 0.f;

    const ushort* kb = k_t + (size_t)b * NN * CC;
    const ushort* vb = v_g + (size_t)b * CC * NN;

    auto stage_tile = [&](int d, int jt) {
        bf16x8 kr[2], vr[2];
        #pragma unroll
        for (int is = 0; is < 2; is++) {
            int s = is * 512 + t;
            kr[is] = *(const bf16x8*)(kb + (size_t)(jt + (s >> 5)) * CC + (s & 31) * 8);
            vr[is] = *(const bf16x8*)(vb + (size_t)(s >> 2) * NN + jt + (s & 3) * 8);
        }
        #pragma unroll
        for (int is = 0; is < 2; is++) {
            int s = is * 512 + t;
            int jr = s >> 5, cc = s & 31;
            *(bf16x8*)((ushort*)k_lds[d] + jr * 256 + ((cc ^ (jr & 7)) * 8)) = kr[is];
            int cr = s >> 2, cv = s & 3;
            *(bf16x8*)((ushort*)v_lds[d] + cr * 32 + ((cv ^ ((cr ^ (cr >> 2)) & 3)) * 8)) = vr[is];
        }
    };

    stage_tile(0, jbase);
    int niter = segn >> 5;

    int r0 = w * 32 + l15;
    int r1 = r0 + 16;
    int half = (g & 1) * 4;

    for (int it = 0; it < niter; it++) {
        int d = it & 1;
        __syncthreads();
        const ushort* kl = k_lds[d];
        const ushort* vl = v_lds[d];

        // S^T = K Q^T, 4 independent chains (2 jg x 2 rb) sharing bk loads.
        // lane holds S[j = jg*16 + g*4 + e][i = l15 (+16 for rb1)]
        f32x4 s00 = {0.f, 0.f, 0.f, 0.f}, s01 = s00, s10 = s00, s11 = s00;
        {
            const ushort* krow = kl + l15 * 256;
            int xj = l15 & 7;
            __builtin_amdgcn_s_setprio(1);
            #pragma unroll
            for (int kk = 0; kk < 8; kk++) {
                int off = ((kk * 4 + g) ^ xj) * 8;
                bf16x8 bk0 = *(const bf16x8*)(krow + off);
                bf16x8 bk1 = *(const bf16x8*)(krow + 16 * 256 + off);
                MFMA16(s00, bk0, qf0[kk]);
                MFMA16(s10, bk0, qf1[kk]);
                MFMA16(s01, bk1, qf0[kk]);
                MFMA16(s11, bk1, qf1[kk]);
            }
            __builtin_amdgcn_s_setprio(0);
        }

        // softmax + P pack per jg (p = exp2(S), log2e folded into Q)
        #pragma unroll
        for (int jg = 0; jg < 2; jg++) {
            f32x4 sa = jg ? s01 : s00;
            f32x4 sb = jg ? s11 : s10;
            float p00 = exp2f(sa[0]), p01 = exp2f(sa[1]);
            float p02 = exp2f(sa[2]), p03 = exp2f(sa[3]);
            float p10 = exp2f(sb[0]), p11 = exp2f(sb[1]);
            float p12 = exp2f(sb[2]), p13 = exp2f(sb[3]);
            l0 += (p00 + p01) + (p02 + p03);
            l1 += (p10 + p11) + (p12 + p13);
            uint lo0 = cvt_pk_bf16(p00, p01), hi0 = cvt_pk_bf16(p02, p03);
            uint lo1 = cvt_pk_bf16(p10, p11), hi1 = cvt_pk_bf16(p12, p13);
            int c16 = jg * 2 + (g >> 1);
            uint2 u0; u0.x = lo0; u0.y = hi0;
            uint2 u1; u1.x = lo1; u1.y = hi1;
            *(uint2*)(p_lds + r0 * 32 + ((c16 ^ (r0 & 3)) * 8) + half) = u0;
            *(uint2*)(p_lds + r1 * 32 + ((c16 ^ (r1 & 3)) * 8) + half) = u1;
        }

        // P A-fragments (wave-private rows; lgkmcnt orders write->read)
        bf16x8 pa0 = *(const bf16x8*)(p_lds + r0 * 32 + ((g ^ (r0 & 3)) * 8));
        bf16x8 pa1 = *(const bf16x8*)(p_lds + r1 * 32 + ((g ^ (r1 & 3)) * 8));

        // O += P V^T (V fragment shared by both row-blocks)
        __builtin_amdgcn_s_setprio(1);
        #pragma unroll
        for (int tc = 0; tc < 16; tc++) {
            int c = tc * 16 + l15;
            bf16x8 vf = *(const bf16x8*)(vl + c * 32 + ((g ^ ((c ^ (c >> 2)) & 3)) * 8));
            MFMA16(O0[tc], pa0, vf);
            MFMA16(O1[tc], pa1, vf);
        }
        __builtin_amdgcn_s_setprio(0);

        // stage next tile (loads + writes in one tight window — R10 proven placement)
        if (it + 1 < niter) stage_tile(d ^ 1, jbase + (it + 1) * 32);
    }

    // l lives per (l15, g): reduce across the 4 g-groups
    l0 += __shfl_xor(l0, 16, 64); l1 += __shfl_xor(l1, 16, 64);
    l0 += __shfl_xor(l0, 32, 64); l1 += __shfl_xor(l1, 32, 64);

    size_t obase = (size_t)(seg * BB + b) * NN + i0;
    if (g == 0) {
        l_part[obase + w * 32 + l15] = l0;
        l_part[obase + w * 32 + 16 + l15] = l1;
    }
    #pragma unroll
    for (int e = 0; e < 4; e++) {
        int ro = w * 32 + g * 4 + e;
        float* orow0 = O_part + (obase + ro) * CC + l15;
        float* orow1 = O_part + (obase + ro + 16) * CC + l15;
        #pragma unroll
        for (int tc = 0; tc < 16; tc++) {
            orow0[tc * 16] = O0[tc][e];
            orow1[tc * 16] = O1[tc][e];
        }
    }
}

// ---------------- merge partial segments -> out_t bf16 (fully coalesced) ----------------
__global__ __launch_bounds__(256) void merge_kernel(
    const float* __restrict__ O_part, const float* __restrict__ l_part,
    ushort* __restrict__ out_t, int S)
{
    int idx = blockIdx.x * 256 + threadIdx.x;
    int row = idx >> 6;
    float lsum = 0.f;
    for (int s = 0; s < S; s++) lsum += l_part[(size_t)s * BB * NN + row];
    float inv = 1.0f / fmaxf(lsum, 1e-20f);

    f32x4 acc = {0.f, 0.f, 0.f, 0.f};
    for (int s = 0; s < S; s++) {
        f32x4 v = *(const f32x4*)(O_part + ((size_t)s * BB * NN * CC) + (size_t)idx * 4);
        acc.x += v.x; acc.y += v.y; acc.z += v.z; acc.w += v.w;
    }
    ushort4 o;
    o.x = f2bf(acc.x * inv);
    o.y = f2bf(acc.y * inv);
    o.z = f2bf(acc.z * inv);
    o.w = f2bf(acc.w * inv);
    *(ushort4*)(out_t + (size_t)idx * 4) = o;
}

// ---------------- proj GEMM + bias + residual (bf16 weights) ----------------
__global__ __launch_bounds__(256) void proj_kernel(
    const ushort* __restrict__ out_t, const ushort* __restrict__ wp,
    const float* __restrict__ proj_b, const float* __restrict__ x,
    float* __restrict__ out)
{
    int b = blockIdx.z;
    int d0 = blockIdx.x * 64;
    int i0 = blockIdx.y * 256;
    int t = threadIdx.x, w = t >> 6, l = t & 63, l15 = l & 15, g = l >> 4;
    __shared__ ushort a_lds[64 * 256];

    #pragma unroll
    for (int it = 0; it < 8; it++) {
        int cid = it * 256 + t;
        int dd = cid >> 5, cc = cid & 31;
        bf16x8 a = *(const bf16x8*)(wp + (size_t)(d0 + dd) * CC + cc * 8);
        *(bf16x8*)(a_lds + dd * 256 + (cc ^ (dd & 7)) * 8) = a;
    }
    __syncthreads();

    f32x4 acc[16];
    #pragma unroll
    for (int it = 0; it < 16; it++) { f32x4 z = {0.f, 0.f, 0.f, 0.f}; acc[it] = z; }
    int dl = w * 16 + l15;
    #pragma unroll
    for (int kk = 0; kk < 8; kk++) {
        int cc = kk * 4 + g;
        bf16x8 af = *(const bf16x8*)(a_lds + dl * 256 + (cc ^ (dl & 7)) * 8);
        #pragma unroll
        for (int it = 0; it < 16; it++) {
            bf16x8 bfr = *(const bf16x8*)(out_t + (size_t)(b * NN + i0 + it * 16 + l15) * CC + kk * 32 + g * 8);
            MFMA16(acc[it], af, bfr);
        }
    }
    int dbase = d0 + w * 16 + g * 4;
    f32x4 pb = *(const f32x4*)(proj_b + dbase);
    #pragma unroll
    for (int it = 0; it < 16; it++) {
        int i = i0 + it * 16 + l15;
        #pragma unroll
        for (int e = 0; e < 4; e++) {
            int off = (b * CC + dbase + e) * NN + i;
            out[off] = acc[it][e] + pb[e] + x[off];
        }
    }
}

extern "C" void kernel_launch(void* const* d_in, const int* in_sizes, int n_in,
                              void* d_out, int out_size, void* d_ws, size_t ws_size,
                              hipStream_t stream) {
    const float* x      = (const float*)d_in[0];
    const float* gamma  = (const float*)d_in[1];
    const float* beta   = (const float*)d_in[2];
    const float* qkv_w  = (const float*)d_in[3];
    const float* qkv_b  = (const float*)d_in[4];
    const float* proj_w = (const float*)d_in[5];
    const float* proj_b = (const float*)d_in[6];
    float* out = (float*)d_out;

    char* ws = (char*)d_ws;
    float* part   = (float*)ws;                       // 2048 B
    float* stats  = (float*)(ws + 2048);              // to 4096
    ushort* wq    = (ushort*)(ws + 4096);             // 384 KiB
    ushort* wp    = (ushort*)(ws + 4096 + 393216);    // 128 KiB -> ends 528384
    ushort* xn_t  = (ushort*)(ws + 528384);
    ushort* q_t   = (ushort*)(ws + 528384 + 1ull * 8388608);
    ushort* k_t   = (ushort*)(ws + 528384 + 2ull * 8388608);
    ushort* v_g   = (ushort*)(ws + 528384 + 3ull * 8388608);
    ushort* out_t = xn_t;

    size_t mlbase = 528384 + 4ull * 8388608;
    float* l_part = (float*)(ws + mlbase);
    size_t obase  = mlbase + 1048576;
    float* O_part = (float*)(ws + obase);

    int S = 1;
    if (ws_size >= obase + 4ull * 16777216) S = 4;
    else if (ws_size >= obase + 2ull * 16777216) S = 2;

    prep_w<<<256, 256, 0, stream>>>(qkv_w, proj_w, wq, wp);
    stats_part<<<dim3(64, 4), 256, 0, stream>>>(x, part);
    stats_final<<<1, 256, 0, stream>>>(part, stats);
    norm_t_kernel<<<dim3(128, 8, 4), 256, 0, stream>>>(x, gamma, beta, stats, xn_t);
    qkv_kernel<<<dim3(2, 64, 4), 256, 0, stream>>>(xn_t, wq, qkv_b, q_t, k_t, v_g);
    flash_kernel<<<dim3(16, S, 4), 512, 0, stream>>>(q_t, k_t, v_g, O_part, l_part, NN / S);
    merge_kernel<<<4096, 256, 0, stream>>>(O_part, l_part, out_t, S);
    proj_kernel<<<dim3(4, 16, 4), 256, 0, stream>>>(out_t, wp, proj_b, x, out);
}